// Round 1
// baseline (1686.307 us; speedup 1.0000x reference)
//
#include <hip/hip_runtime.h>
#include <stdint.h>

#define NB 4
#define CIN 512
#define PIX 2500
#define KTOT 4608
#define NBOX 22500
#define NPRE 6000
#define NPOST 300
#define NWORD 94
#define CAP 16384

#define O_LOCS   0
#define O_SCORES 360000
#define O_ROIS   540000
#define O_RIDX   544800
#define O_ANCH   546000

// workspace offsets (bytes). mask reuses xpad region (xpad dead after k_conv).
#define WO_XPAD  0ull
#define WO_MASK  0ull
#define WO_FEATT 22151168ull
#define WO_WT    42631168ull
#define WO_BOXES 42745856ull
#define WO_DKEY  44185856ull
#define WO_ORDER 44545856ull
#define WO_BOX6K 44641856ull
#define WO_VALID 45025856ull

__device__ __forceinline__ float rd_dim(const int* p) {
  int v = *p;
  if (v > 0 && v < 1000000) return (float)v;   // int32 scalar
  return __int_as_float(v);                    // float32 scalar
}

// ---------------- pad input: (4,512,50,50) -> (4,512,52,52) zero border ----
__global__ void k_pad(const float* __restrict__ x, float* __restrict__ xpad) {
  int idx = blockIdx.x * 256 + threadIdx.x;
  if (idx >= NB * CIN * 2704) return;
  int cc = idx % 52, r = (idx / 52) % 52, ch = idx / 2704;
  float v = 0.f;
  if (r >= 1 && r <= 50 && cc >= 1 && cc <= 50)
    v = x[(size_t)ch * 2500 + (r - 1) * 50 + (cc - 1)];
  xpad[idx] = v;
}

// ---------------- pack head weights: wt[(c4*56+j)*4+i] = W[j][c4*4+i] -------
__global__ void k_wt(const float* __restrict__ loc_w, const float* __restrict__ score_w,
                     float* __restrict__ wt) {
  int idx = blockIdx.x * 256 + threadIdx.x;
  if (idx >= 128 * 56 * 4) return;
  int i = idx & 3, j = (idx >> 2) % 56, c4 = idx / 224;
  int c = c4 * 4 + i;
  float v = 0.f;
  if (j < 36) v = loc_w[(size_t)j * 512 + c];
  else if (j < 54) v = score_w[(size_t)(j - 36) * 512 + c];
  wt[idx] = v;
}

// ---------------- conv1 3x3 512->512 + bias + relu, writes featT[b][p][c] ---
#define BKC 32
__global__ __launch_bounds__(256) void k_conv(const float* __restrict__ xpad,
                                              const float* __restrict__ w,
                                              const float* __restrict__ bias,
                                              float* __restrict__ featT) {
  __shared__ float As[BKC][132];
  __shared__ float Bs[BKC][132];
  int b = blockIdx.z, mt = blockIdx.y, nt = blockIdx.x;
  int t = threadIdx.x;
  int r = t >> 4, c = t & 15;
  const float* xb = xpad + (size_t)b * CIN * 2704;
  int ocb = mt * 128, pxb = nt * 128;
  float acc[8][8];
#pragma unroll
  for (int i = 0; i < 8; i++)
#pragma unroll
    for (int j = 0; j < 8; j++) acc[i][j] = 0.f;

  for (int kb = 0; kb < KTOT; kb += BKC) {
    __syncthreads();
    // stage A: W[ocb..+128][kb..+32] -> As[k][oc]
#pragma unroll
    for (int m = 0; m < 4; m++) {
      int v = t + 256 * m;
      int oc = v >> 3, kq = v & 7;
      float4 f = *(const float4*)(w + (size_t)(ocb + oc) * KTOT + kb + kq * 4);
      As[kq * 4 + 0][oc] = f.x;
      As[kq * 4 + 1][oc] = f.y;
      As[kq * 4 + 2][oc] = f.z;
      As[kq * 4 + 3][oc] = f.w;
    }
    // stage B: im2col gather -> Bs[k][px]
#pragma unroll
    for (int q = 0; q < 16; q++) {
      int k = (t >> 7) + q * 2;
      int px = t & 127;
      int kg = kb + k;
      int ic = (kg * 7282) >> 16;        // kg/9
      int tap = kg - ic * 9;
      int ty = (tap * 11) >> 5;          // tap/3
      int tx = tap - ty * 3;
      int pg = pxb + px;
      int py = (pg * 1311) >> 16;        // pg/50
      int pxc = pg - py * 50;
      Bs[k][px] = xb[(size_t)ic * 2704 + (py + ty) * 52 + (pxc + tx)];
    }
    __syncthreads();
#pragma unroll
    for (int k = 0; k < BKC; k++) {
      float av[8], bv[8];
      *(float4*)&av[0] = *(const float4*)&As[k][r * 8];
      *(float4*)&av[4] = *(const float4*)&As[k][r * 8 + 4];
      *(float4*)&bv[0] = *(const float4*)&Bs[k][c * 8];
      *(float4*)&bv[4] = *(const float4*)&Bs[k][c * 8 + 4];
#pragma unroll
      for (int oi = 0; oi < 8; oi++)
#pragma unroll
        for (int pj = 0; pj < 8; pj++) acc[oi][pj] += av[oi] * bv[pj];
    }
  }
  float bvv[8];
#pragma unroll
  for (int i = 0; i < 8; i++) bvv[i] = bias[ocb + r * 8 + i];
#pragma unroll
  for (int pj = 0; pj < 8; pj++) {
    int p = pxb + c * 8 + pj;
    if (p < PIX) {
      float o[8];
#pragma unroll
      for (int i = 0; i < 8; i++) o[i] = fmaxf(acc[i][pj] + bvv[i], 0.f);
      size_t base = ((size_t)b * PIX + p) * 512 + ocb + r * 8;
      *(float4*)(featT + base) = make_float4(o[0], o[1], o[2], o[3]);
      *(float4*)(featT + base + 4) = make_float4(o[4], o[5], o[6], o[7]);
    }
  }
}

// ---------------- heads: 54 dots/pixel, softmax, decode, keys --------------
__global__ __launch_bounds__(256) void k_heads(const float* __restrict__ featT,
                                               const float* __restrict__ wt4,
                                               const float* __restrict__ loc_b,
                                               const float* __restrict__ score_b,
                                               const int* __restrict__ ihp,
                                               const int* __restrict__ iwp,
                                               float* __restrict__ out,
                                               float* __restrict__ boxes,
                                               uint32_t* __restrict__ dkey) {
  int wid = blockIdx.x * 4 + (threadIdx.x >> 6);
  if (wid >= NB * PIX) return;
  int lane = threadIdx.x & 63;
  int b = wid / PIX, p = wid % PIX;
  int row = lane < 54 ? lane : 54;
  const float* fp = featT + ((size_t)b * PIX + p) * 512;
  float acc = 0.f;
  for (int c4 = 0; c4 < 128; c4++) {
    float4 f = *(const float4*)(fp + c4 * 4);
    float4 wv = *(const float4*)(wt4 + ((size_t)c4 * 56 + row) * 4);
    acc += f.x * wv.x;
    acc += f.y * wv.y;
    acc += f.z * wv.z;
    acc += f.w * wv.w;
  }
  float bi = 0.f;
  if (lane < 36) bi = loc_b[lane];
  else if (lane < 54) bi = score_b[lane - 36];
  acc += bi;
  if (lane < 36) out[O_LOCS + (size_t)b * 90000 + (size_t)p * 36 + lane] = acc;
  else if (lane < 54) out[O_SCORES + (size_t)b * 45000 + (size_t)p * 18 + (lane - 36)] = acc;

  float imgH = rd_dim(ihp), imgW = rd_dim(iwp);
  int gy = p % 50, gx = p / 50;           // transposed-anchor pairing (meshgrid 'ij')
  float sy = 16.f * gy, sx = 16.f * gx;

  int a9 = (lane < 9) ? lane : 0;
  float dy  = __shfl(acc, a9 * 4 + 0);
  float dxv = __shfl(acc, a9 * 4 + 1);
  float dh  = __shfl(acc, a9 * 4 + 2);
  float dw  = __shfl(acc, a9 * 4 + 3);
  float l0  = __shfl(acc, 36 + a9 * 2);
  float l1  = __shfl(acc, 36 + a9 * 2 + 1);

  {
    float rr = (a9 < 3) ? 0.5f : (a9 < 6 ? 1.f : 2.f);
    int si = a9 % 3;
    float ssc = (si == 0) ? 8.f : (si == 1 ? 16.f : 32.f);
    float hb = 16.f * ssc * sqrtf(rr);
    float wb = 16.f * ssc * sqrtf(1.f / rr);
    float ay1 = (8.f - hb * 0.5f) + sy;
    float ax1 = (8.f - wb * 0.5f) + sx;
    float ay2 = (8.f + hb * 0.5f) + sy;
    float ax2 = (8.f + wb * 0.5f) + sx;
    float h = ay2 - ay1, w2d = ax2 - ax1;
    float cy = ay1 + 0.5f * h, cx = ax1 + 0.5f * w2d;
    float cy2 = dy * h + cy, cx2 = dxv * w2d + cx;
    float h2 = expf(dh) * h, ww2 = expf(dw) * w2d;
    float y1 = cy2 - 0.5f * h2, x1 = cx2 - 0.5f * ww2;
    float y2 = cy2 + 0.5f * h2, x2 = cx2 + 0.5f * ww2;
    y1 = fminf(fmaxf(y1, 0.f), imgH);
    x1 = fminf(fmaxf(x1, 0.f), imgW);
    y2 = fminf(fmaxf(y2, 0.f), imgH);
    x2 = fminf(fmaxf(x2, 0.f), imgW);
    bool valid = (y2 - y1 >= 16.f) && (x2 - x1 >= 16.f);
    float m = fmaxf(l0, l1);
    float e0 = expf(l0 - m), e1 = expf(l1 - m);
    float fg = e1 / (e0 + e1);
    float scv = valid ? fg : -INFINITY;
    if (lane < 9) {
      size_t k = (size_t)b * NBOX + (size_t)p * 9 + a9;
      *(float4*)(boxes + k * 4) = make_float4(y1, x1, y2, x2);
      uint32_t u = __float_as_uint(scv);
      uint32_t f2 = (u >> 31) ? ~u : (u | 0x80000000u);
      dkey[k] = ~f2;   // ascending d == descending score
    }
  }
  if (b == 0 && lane < 36) {
    int aa = lane >> 2, dd = lane & 3;
    float rr2 = (aa < 3) ? 0.5f : (aa < 6 ? 1.f : 2.f);
    int si2 = aa % 3;
    float ss2 = (si2 == 0) ? 8.f : (si2 == 1 ? 16.f : 32.f);
    float hb2 = 16.f * ss2 * sqrtf(rr2);
    float wb2 = 16.f * ss2 * sqrtf(1.f / rr2);
    float v;
    if (dd == 0) v = (8.f - hb2 * 0.5f) + sy;
    else if (dd == 1) v = (8.f - wb2 * 0.5f) + sx;
    else if (dd == 2) v = (8.f + hb2 * 0.5f) + sy;
    else v = (8.f + wb2 * 0.5f) + sx;
    out[O_ANCH + (size_t)p * 36 + lane] = v;
  }
}

// ---------------- exact top-6000 (radix-select + bitonic), per batch -------
__global__ void k_topk(const uint32_t* __restrict__ dkey, const float* __restrict__ boxes,
                       uint32_t* __restrict__ order, float* __restrict__ box6k,
                       unsigned long long* __restrict__ validm) {
  extern __shared__ char smem[];
  uint64_t* cand = (uint64_t*)smem;
  uint32_t* hist = (uint32_t*)(smem + (size_t)CAP * 8);
  uint32_t* sc = hist + 256;
  int b = blockIdx.x, tid = threadIdx.x;
  const uint32_t* dk = dkey + (size_t)b * NBOX;
  uint32_t P = 0, need = NPRE;
  for (int pass = 0; pass < 4; pass++) {
    int sh = 24 - 8 * pass;
    for (int i = tid; i < 256; i += 1024) hist[i] = 0;
    __syncthreads();
    for (int i = tid; i < NBOX; i += 1024) {
      uint32_t d = dk[i];
      bool match = (((uint64_t)d >> (sh + 8)) == ((uint64_t)P >> (sh + 8)));
      if (match) atomicAdd(&hist[(d >> sh) & 255u], 1u);
    }
    __syncthreads();
    if (tid == 0) {
      uint32_t cum = 0, v = 0;
      for (; v < 255; v++) {
        if (cum + hist[v] >= need) break;
        cum += hist[v];
      }
      sc[0] = v;
      sc[1] = cum;
    }
    __syncthreads();
    need -= sc[1];
    P |= sc[0] << sh;
    __syncthreads();
  }
  uint32_t Dstar = P;
  if (tid == 0) sc[2] = 0;
  __syncthreads();
  for (int i = tid; i < NBOX; i += 1024) {
    uint32_t d = dk[i];
    if (d <= Dstar) {
      uint32_t pos = atomicAdd(&sc[2], 1u);
      if (pos < CAP) cand[pos] = ((uint64_t)d << 32) | (uint32_t)i;
    }
  }
  __syncthreads();
  uint32_t cnt = sc[2] < CAP ? sc[2] : CAP;
  for (uint32_t i = cnt + tid; i < CAP; i += 1024) cand[i] = ~0ull;
  for (int ksz = 2; ksz <= CAP; ksz <<= 1) {
    for (int jsz = ksz >> 1; jsz > 0; jsz >>= 1) {
      __syncthreads();
      for (int i = tid; i < CAP / 2; i += 1024) {
        int aI = ((i / jsz) * jsz * 2) + (i % jsz);
        int bI = aI + jsz;
        uint64_t xv = cand[aI], yv = cand[bI];
        bool up = ((aI & ksz) == 0);
        if ((xv > yv) == up) { cand[aI] = yv; cand[bI] = xv; }
      }
    }
  }
  __syncthreads();
  for (int r = tid; r < NPRE; r += 1024) {
    uint64_t kk = cand[r];
    uint32_t idx = (uint32_t)kk;
    order[(size_t)b * NPRE + r] = idx;
    float4 bx = *(const float4*)(boxes + ((size_t)b * NBOX + idx) * 4);
    *(float4*)(box6k + ((size_t)b * NPRE + r) * 4) = bx;
  }
  for (int wi = tid; wi < NWORD; wi += 1024) {
    unsigned long long m = 0ull;
    for (int bb = 0; bb < 64; bb++) {
      int r = wi * 64 + bb;
      if (r < NPRE) {
        uint32_t d = (uint32_t)(cand[r] >> 32);
        if (d < 0xFF800000u) m |= (1ull << bb);   // score > -inf
      }
    }
    validm[b * NWORD + wi] = m;
  }
}

// ---------------- NMS suppression bitmask ----------------------------------
__global__ __launch_bounds__(256) void k_mask(const float* __restrict__ box6k,
                                              unsigned long long* __restrict__ mask) {
  int b = blockIdx.z, it = blockIdx.x, wt = blockIdx.y;
  int t = threadIdx.x;
  int il = t & 31, wl = t >> 5;
  __shared__ float bi[32][4];
  __shared__ float bj[512][4];
  if (t < 128) {
    int ii = it * 32 + (t >> 2);
    if (ii > NPRE - 1) ii = NPRE - 1;
    bi[t >> 2][t & 3] = box6k[((size_t)b * NPRE + ii) * 4 + (t & 3)];
  }
#pragma unroll
  for (int q = 0; q < 2; q++) {
    int v = t + 256 * q;
    int jg = wt * 512 + v;
    float4 f = make_float4(0.f, 0.f, 0.f, 0.f);
    if (jg < NPRE) f = *(const float4*)(box6k + ((size_t)b * NPRE + jg) * 4);
    *(float4*)&bj[v][0] = f;
  }
  __syncthreads();
  int i = it * 32 + il;
  int w = wt * 8 + wl;
  if (i >= NPRE || w >= NWORD) return;
  float y1 = bi[il][0], x1 = bi[il][1], y2 = bi[il][2], x2 = bi[il][3];
  float ar = (y2 - y1) * (x2 - x1);
  unsigned long long m = 0ull;
  int jbase = w * 64;
  for (int jj = 0; jj < 64; jj++) {
    int j = jbase + jj;
    int js = wl * 64 + jj;
    float jy1 = bj[js][0], jx1 = bj[js][1], jy2 = bj[js][2], jx2 = bj[js][3];
    float tlY = fmaxf(y1, jy1), tlX = fmaxf(x1, jx1);
    float brY = fminf(y2, jy2), brX = fminf(x2, jx2);
    float ih = fmaxf(brY - tlY, 0.f), iw2 = fmaxf(brX - tlX, 0.f);
    float inter = ih * iw2;
    float arj = (jy2 - jy1) * (jx2 - jx1);
    float iou = inter / (ar + arj - inter);
    if (iou > 0.7f && j > i && j < NPRE) m |= (1ull << jj);
  }
  mask[((size_t)b * NPRE + i) * NWORD + w] = m;
}

// ---------------- sequential NMS scan + output (one wave per batch) --------
__global__ void k_scan(const unsigned long long* __restrict__ mask,
                       const unsigned long long* __restrict__ validm,
                       const float* __restrict__ box6k, float* __restrict__ out) {
  int b = blockIdx.x;
  int lane = threadIdx.x;
  const unsigned long long* mb = mask + (size_t)b * NPRE * NWORD;
  unsigned long long rm0 = 0ull, rm1 = 0ull;
  unsigned long long v0 = (lane < NWORD) ? validm[b * NWORD + lane] : 0ull;
  unsigned long long v1 = (lane + 64 < NWORD) ? validm[b * NWORD + lane + 64] : 0ull;
  __shared__ int keptIdx[NPOST];
  int cnt = 0;
  for (int i = 0; i < NPRE; i++) {
    int w = i >> 6, bp = i & 63;
    unsigned long long rw = (w < 64) ? __shfl(rm0, w) : __shfl(rm1, w - 64);
    unsigned long long vw = (w < 64) ? __shfl(v0, w) : __shfl(v1, w - 64);
    bool keep = ((vw >> bp) & 1ull) && !((rw >> bp) & 1ull);
    if (keep) {
      if (lane == 0) keptIdx[cnt] = i;
      cnt++;
      if (cnt >= NPOST) break;
      unsigned long long m0 = (lane < NWORD) ? mb[(size_t)i * NWORD + lane] : 0ull;
      unsigned long long m1 = (lane + 64 < NWORD) ? mb[(size_t)i * NWORD + lane + 64] : 0ull;
      rm0 |= m0;
      rm1 |= m1;
    }
  }
  __syncthreads();
  for (int r = lane; r < NPOST; r += 64) {
    float4 bx = make_float4(0.f, 0.f, 0.f, 0.f);
    if (r < cnt) bx = *(const float4*)(box6k + ((size_t)b * NPRE + keptIdx[r]) * 4);
    *(float4*)(out + O_ROIS + ((size_t)b * NPOST + r) * 4) = bx;
    out[O_RIDX + b * NPOST + r] = (float)b;
  }
}

extern "C" void kernel_launch(void* const* d_in, const int* in_sizes, int n_in,
                              void* d_out, int out_size, void* d_ws, size_t ws_size,
                              hipStream_t stream) {
  const float* x       = (const float*)d_in[0];
  const float* conv1_w = (const float*)d_in[1];
  const float* conv1_b = (const float*)d_in[2];
  const float* score_w = (const float*)d_in[3];
  const float* score_b = (const float*)d_in[4];
  const float* loc_w   = (const float*)d_in[5];
  const float* loc_b   = (const float*)d_in[6];
  const int* ihp = (const int*)d_in[7];
  const int* iwp = (const int*)d_in[8];
  float* out = (float*)d_out;
  char* ws = (char*)d_ws;
  float* xpad  = (float*)(ws + WO_XPAD);
  float* featT = (float*)(ws + WO_FEATT);
  float* wt    = (float*)(ws + WO_WT);
  float* boxes = (float*)(ws + WO_BOXES);
  uint32_t* dkey  = (uint32_t*)(ws + WO_DKEY);
  uint32_t* order = (uint32_t*)(ws + WO_ORDER);
  float* box6k = (float*)(ws + WO_BOX6K);
  unsigned long long* validm = (unsigned long long*)(ws + WO_VALID);
  unsigned long long* mask   = (unsigned long long*)(ws + WO_MASK);

  k_pad<<<(NB * CIN * 2704 + 255) / 256, 256, 0, stream>>>(x, xpad);
  k_wt<<<(128 * 56 * 4 + 255) / 256, 256, 0, stream>>>(loc_w, score_w, wt);
  dim3 gc(20, 4, NB);
  k_conv<<<gc, 256, 0, stream>>>(xpad, conv1_w, conv1_b, featT);
  k_heads<<<(NB * PIX + 3) / 4, 256, 0, stream>>>(featT, wt, loc_b, score_b, ihp, iwp,
                                                  out, boxes, dkey);
  hipFuncSetAttribute((const void*)k_topk, hipFuncAttributeMaxDynamicSharedMemorySize,
                      CAP * 8 + 4096);
  k_topk<<<NB, 1024, CAP * 8 + 4096, stream>>>(dkey, boxes, order, box6k, validm);
  dim3 gm(188, 12, NB);
  k_mask<<<gm, 256, 0, stream>>>(box6k, mask);
  k_scan<<<NB, 64, 0, stream>>>(mask, validm, box6k, out);
}

// Round 2
// 944.338 us; speedup vs baseline: 1.7857x; 1.7857x over previous
//
#include <hip/hip_runtime.h>
#include <stdint.h>

#define NB 4
#define CIN 512
#define PIX 2500
#define KTOT 4608
#define NBOX 22500
#define NPRE 6000
#define NPOST 300
#define NWORD 94
#define CAP 16384

#define O_LOCS   0
#define O_SCORES 360000
#define O_ROIS   540000
#define O_RIDX   544800
#define O_ANCH   546000

// xT geometry: per image, 64 front-slack + 2704 body + 192 back-slack pixel rows, 512 ch fp16
#define XT_ROWS 2960
#define XT_FRONT 64
#define XT_IMG (XT_ROWS * 512)          // fp16 elements per image
#define XT_SPLIT_BYTES ((size_t)NB * XT_IMG * 2)   // 12,124,160

// workspace offsets (bytes)
#define WO_XT1   0ull
#define WO_XT2   12124160ull
#define WO_WSA   24248320ull
#define WO_WSB   28966912ull
#define WO_FEATP 33685504ull            // 2 ksplits x 4 b x 2500 p x 512 oc fp32 = 40,960,000
#define WO_WT    74645504ull
#define WO_BOXES 74760192ull
#define WO_DKEY  76200192ull
#define WO_BOX6K 76560192ull
#define WO_VALID 76944192ull
#define WO_MASK  0ull                   // aliases xT (dead after conv)

#define FEATP_HALF 5120000              // floats per ksplit

typedef _Float16 h8 __attribute__((ext_vector_type(8)));
typedef float f16a __attribute__((ext_vector_type(16)));
typedef unsigned int u32;

__device__ __forceinline__ void gll16(const void* g, void* l) {
  __builtin_amdgcn_global_load_lds((const __attribute__((address_space(1))) u32*)g,
                                   (__attribute__((address_space(3))) u32*)l, 16, 0, 0);
}

__device__ __forceinline__ float rd_dim(const int* p) {
  int v = *p;
  if (v > 0 && v < 1000000) return (float)v;
  return __int_as_float(v);
}

// ---------------- zero xT (both splits, incl. slack + borders) --------------
__global__ void k_zero(u32* __restrict__ xt) {
  size_t n = (2 * XT_SPLIT_BYTES) / 4;
  for (size_t i = blockIdx.x * 256ull + threadIdx.x; i < n; i += (size_t)gridDim.x * 256)
    xt[i] = 0u;
}

// ---------------- split + transpose x -> xT[b][pix][ic] fp16 hi/lo ---------
__global__ void k_xT(const float* __restrict__ x, _Float16* __restrict__ x1,
                     _Float16* __restrict__ x2) {
  __shared__ float sx[3200];            // [64 ic][50 c]
  int chunk = blockIdx.x, r0 = blockIdx.y, b = blockIdx.z;
  int t = threadIdx.x;
  int ic0 = chunk * 64;
  for (int i = t; i < 3200; i += 256) {
    int icl = i / 50, c = i - icl * 50;
    sx[i] = x[(((size_t)b * 512 + ic0 + icl) * 50 + r0) * 50 + c];
  }
  __syncthreads();
  for (int j = t; j < 3200; j += 256) {
    int c = j >> 6, icl = j & 63;
    float v = sx[icl * 50 + c];
    _Float16 h1 = (_Float16)v;
    _Float16 h2 = (_Float16)(v - (float)h1);
    size_t dst = (size_t)b * XT_IMG + (size_t)(XT_FRONT + (r0 + 1) * 52 + (c + 1)) * 512 + ic0 + icl;
    x1[dst] = h1;
    x2[dst] = h2;
  }
}

// ---------------- split + reorder weights: ws[oc][tap*512+ic] fp16 ---------
__global__ void k_splitw(const float* __restrict__ w, _Float16* __restrict__ wA,
                         _Float16* __restrict__ wB) {
  int n = 512 * KTOT;
  for (int idx = blockIdx.x * 256 + threadIdx.x; idx < n; idx += gridDim.x * 256) {
    int oc = idx / KTOT;
    int rem = idx - oc * KTOT;
    int tp = rem >> 9, ic = rem & 511;
    float v = w[((size_t)oc * 512 + ic) * 9 + tp];
    _Float16 h1 = (_Float16)v;
    wA[idx] = h1;
    wB[idx] = (_Float16)(v - (float)h1);
  }
}

// ---------------- pack head weights: wt[(c4*56+j)*4+i] = W[j][c4*4+i] ------
__global__ void k_wt(const float* __restrict__ loc_w, const float* __restrict__ score_w,
                     float* __restrict__ wt) {
  int idx = blockIdx.x * 256 + threadIdx.x;
  if (idx >= 128 * 56 * 4) return;
  int i = idx & 3, j = (idx >> 2) % 56, c4 = idx / 224;
  int c = c4 * 4 + i;
  float v = 0.f;
  if (j < 36) v = loc_w[(size_t)j * 512 + c];
  else if (j < 54) v = score_w[(size_t)(j - 36) * 512 + c];
  wt[idx] = v;
}

// ---------------- conv via split-fp16 MFMA, K-split 2, partial fp32 --------
__global__ __launch_bounds__(256, 2) void k_conv(
    const _Float16* __restrict__ xs1, const _Float16* __restrict__ xs2,
    const _Float16* __restrict__ wsA, const _Float16* __restrict__ wsB,
    float* __restrict__ featP) {
  __shared__ _Float16 lds[16384];       // 32 regions x 1KB (64 lanes x 16B)
  int nt = blockIdx.x, mt = blockIdx.y, bz = blockIdx.z;
  int b = bz >> 1, ks = bz & 1;
  int t = threadIdx.x, lane = t & 63, w = t >> 6;
  int mh = w & 1, nh = w >> 1;
  int mb = mt * 128, nb = nt * 128;
  int l31 = lane & 31, l5 = lane >> 5;
  const _Float16* xi1 = xs1 + (size_t)b * XT_IMG + (size_t)XT_FRONT * 512;
  const _Float16* xi2 = xs2 + (size_t)b * XT_IMG + (size_t)XT_FRONT * 512;

  f16a acc[2][2];
#pragma unroll
  for (int i = 0; i < 2; i++)
#pragma unroll
    for (int j = 0; j < 2; j++)
#pragma unroll
      for (int e = 0; e < 16; e++) acc[i][j][e] = 0.f;

  for (int kk = 0; kk < 72; kk++) {
    int kb = ks * 2304 + kk * 32;
    int tap = kb >> 9, ic0 = kb & 511;
    int off = (tap / 3 - 1) * 52 + (tap % 3) - 1;
    // stage 32 x 1KB regions in fragment-linear order (8 issues per wave)
#pragma unroll
    for (int u = 0; u < 8; u++) {
      int i = w * 8 + u;
      if (i < 16) {                      // A region: s=i>>3, ms=(i>>1)&3, k16=i&1
        int s = i >> 3, ms = (i >> 1) & 3, k16 = i & 1;
        const _Float16* wp = s ? wsB : wsA;
        const _Float16* src = wp + (size_t)(mb + ms * 32 + l31) * KTOT + kb + k16 * 16 + l5 * 8;
        gll16(src, &lds[i * 512]);
      } else {                           // B region
        int j = i - 16;
        int s = j >> 3, ns = (j >> 1) & 3, k16 = j & 1;
        const _Float16* xp = s ? xi2 : xi1;
        int qp = nb + ns * 32 + l31 + off;
        const _Float16* src = xp + (ptrdiff_t)qp * 512 + ic0 + k16 * 16 + l5 * 8;
        gll16(src, &lds[(16 + j) * 512]);
      }
    }
    __syncthreads();                     // vmcnt(0) drain -> LDS tiles ready
    h8 af[2][2][2], bf[2][2][2];         // [split][frag][k16]
#pragma unroll
    for (int s = 0; s < 2; s++)
#pragma unroll
      for (int f = 0; f < 2; f++)
#pragma unroll
        for (int k16 = 0; k16 < 2; k16++) {
          int ms = mh * 2 + f, ns = nh * 2 + f;
          af[s][f][k16] = *(const h8*)&lds[((s * 4 + ms) * 2 + k16) * 512 + lane * 8];
          bf[s][f][k16] = *(const h8*)&lds[(16 + (s * 4 + ns) * 2 + k16) * 512 + lane * 8];
        }
#pragma unroll
    for (int k16 = 0; k16 < 2; k16++)
#pragma unroll
      for (int mf = 0; mf < 2; mf++)
#pragma unroll
        for (int nf = 0; nf < 2; nf++) {
          acc[mf][nf] = __builtin_amdgcn_mfma_f32_32x32x16_f16(af[0][mf][k16], bf[0][nf][k16], acc[mf][nf], 0, 0, 0);
          acc[mf][nf] = __builtin_amdgcn_mfma_f32_32x32x16_f16(af[0][mf][k16], bf[1][nf][k16], acc[mf][nf], 0, 0, 0);
          acc[mf][nf] = __builtin_amdgcn_mfma_f32_32x32x16_f16(af[1][mf][k16], bf[0][nf][k16], acc[mf][nf], 0, 0, 0);
        }
    __syncthreads();                     // readers done before next overwrite
  }

  float* fp = featP + (size_t)ks * FEATP_HALF;
#pragma unroll
  for (int mf = 0; mf < 2; mf++)
#pragma unroll
    for (int nf = 0; nf < 2; nf++) {
      int q = nb + nh * 64 + nf * 32 + l31;
      int r = q / 52, c = q - r * 52;
      if (r >= 1 && r <= 50 && c >= 1 && c <= 50) {
        int p = (r - 1) * 50 + (c - 1);
        int oc0 = mb + mh * 64 + mf * 32 + 4 * l5;
        size_t base = ((size_t)b * PIX + p) * 512 + oc0;
#pragma unroll
        for (int g = 0; g < 4; g++) {
          float4 v = make_float4(acc[mf][nf][4 * g + 0], acc[mf][nf][4 * g + 1],
                                 acc[mf][nf][4 * g + 2], acc[mf][nf][4 * g + 3]);
          *(float4*)&fp[base + 8 * g] = v;
        }
      }
    }
}

// ---------------- heads: sum partials + bias + relu, 54 dots, decode -------
__global__ __launch_bounds__(256) void k_heads(const float* __restrict__ featP,
                                               const float* __restrict__ wt4,
                                               const float* __restrict__ conv_b,
                                               const float* __restrict__ loc_b,
                                               const float* __restrict__ score_b,
                                               const int* __restrict__ ihp,
                                               const int* __restrict__ iwp,
                                               float* __restrict__ out,
                                               float* __restrict__ boxes,
                                               uint32_t* __restrict__ dkey) {
  int wid = blockIdx.x * 4 + (threadIdx.x >> 6);
  if (wid >= NB * PIX) return;
  int lane = threadIdx.x & 63;
  int b = wid / PIX, p = wid % PIX;
  int row = lane < 54 ? lane : 54;
  const float* f0 = featP + ((size_t)b * PIX + p) * 512;
  const float* f1 = f0 + FEATP_HALF;
  float acc = 0.f;
  for (int c4 = 0; c4 < 128; c4++) {
    float4 u = *(const float4*)(f0 + c4 * 4);
    float4 v = *(const float4*)(f1 + c4 * 4);
    float4 bb = *(const float4*)(conv_b + c4 * 4);
    float4 wv = *(const float4*)(wt4 + ((size_t)c4 * 56 + row) * 4);
    acc += fmaxf(u.x + v.x + bb.x, 0.f) * wv.x;
    acc += fmaxf(u.y + v.y + bb.y, 0.f) * wv.y;
    acc += fmaxf(u.z + v.z + bb.z, 0.f) * wv.z;
    acc += fmaxf(u.w + v.w + bb.w, 0.f) * wv.w;
  }
  float bi = 0.f;
  if (lane < 36) bi = loc_b[lane];
  else if (lane < 54) bi = score_b[lane - 36];
  acc += bi;
  if (lane < 36) out[O_LOCS + (size_t)b * 90000 + (size_t)p * 36 + lane] = acc;
  else if (lane < 54) out[O_SCORES + (size_t)b * 45000 + (size_t)p * 18 + (lane - 36)] = acc;

  float imgH = rd_dim(ihp), imgW = rd_dim(iwp);
  int gy = p % 50, gx = p / 50;           // transposed-anchor pairing (meshgrid 'ij')
  float sy = 16.f * gy, sx = 16.f * gx;

  int a9 = (lane < 9) ? lane : 0;
  float dy  = __shfl(acc, a9 * 4 + 0);
  float dxv = __shfl(acc, a9 * 4 + 1);
  float dh  = __shfl(acc, a9 * 4 + 2);
  float dw  = __shfl(acc, a9 * 4 + 3);
  float l0  = __shfl(acc, 36 + a9 * 2);
  float l1  = __shfl(acc, 36 + a9 * 2 + 1);

  {
    float rr = (a9 < 3) ? 0.5f : (a9 < 6 ? 1.f : 2.f);
    int si = a9 % 3;
    float ssc = (si == 0) ? 8.f : (si == 1 ? 16.f : 32.f);
    float hb = 16.f * ssc * sqrtf(rr);
    float wb = 16.f * ssc * sqrtf(1.f / rr);
    float ay1 = (8.f - hb * 0.5f) + sy;
    float ax1 = (8.f - wb * 0.5f) + sx;
    float ay2 = (8.f + hb * 0.5f) + sy;
    float ax2 = (8.f + wb * 0.5f) + sx;
    float h = ay2 - ay1, w2d = ax2 - ax1;
    float cy = ay1 + 0.5f * h, cx = ax1 + 0.5f * w2d;
    float cy2 = dy * h + cy, cx2 = dxv * w2d + cx;
    float h2 = expf(dh) * h, ww2 = expf(dw) * w2d;
    float y1 = cy2 - 0.5f * h2, x1 = cx2 - 0.5f * ww2;
    float y2 = cy2 + 0.5f * h2, x2 = cx2 + 0.5f * ww2;
    y1 = fminf(fmaxf(y1, 0.f), imgH);
    x1 = fminf(fmaxf(x1, 0.f), imgW);
    y2 = fminf(fmaxf(y2, 0.f), imgH);
    x2 = fminf(fmaxf(x2, 0.f), imgW);
    bool valid = (y2 - y1 >= 16.f) && (x2 - x1 >= 16.f);
    float m = fmaxf(l0, l1);
    float e0 = expf(l0 - m), e1 = expf(l1 - m);
    float fg = e1 / (e0 + e1);
    float scv = valid ? fg : -INFINITY;
    if (lane < 9) {
      size_t k = (size_t)b * NBOX + (size_t)p * 9 + a9;
      *(float4*)(boxes + k * 4) = make_float4(y1, x1, y2, x2);
      uint32_t u = __float_as_uint(scv);
      uint32_t f2 = (u >> 31) ? ~u : (u | 0x80000000u);
      dkey[k] = ~f2;   // ascending d == descending score
    }
  }
  if (b == 0 && lane < 36) {
    int aa = lane >> 2, dd = lane & 3;
    float rr2 = (aa < 3) ? 0.5f : (aa < 6 ? 1.f : 2.f);
    int si2 = aa % 3;
    float ss2 = (si2 == 0) ? 8.f : (si2 == 1 ? 16.f : 32.f);
    float hb2 = 16.f * ss2 * sqrtf(rr2);
    float wb2 = 16.f * ss2 * sqrtf(1.f / rr2);
    float v;
    if (dd == 0) v = (8.f - hb2 * 0.5f) + sy;
    else if (dd == 1) v = (8.f - wb2 * 0.5f) + sx;
    else if (dd == 2) v = (8.f + hb2 * 0.5f) + sy;
    else v = (8.f + wb2 * 0.5f) + sx;
    out[O_ANCH + (size_t)p * 36 + lane] = v;
  }
}

// ---------------- exact top-6000 (radix-select + bitonic), per batch -------
__global__ void k_topk(const uint32_t* __restrict__ dkey, const float* __restrict__ boxes,
                       uint32_t* __restrict__ order, float* __restrict__ box6k,
                       unsigned long long* __restrict__ validm) {
  extern __shared__ char smem[];
  uint64_t* cand = (uint64_t*)smem;
  uint32_t* hist = (uint32_t*)(smem + (size_t)CAP * 8);
  uint32_t* sc = hist + 256;
  int b = blockIdx.x, tid = threadIdx.x;
  const uint32_t* dk = dkey + (size_t)b * NBOX;
  uint32_t P = 0, need = NPRE;
  for (int pass = 0; pass < 4; pass++) {
    int sh = 24 - 8 * pass;
    for (int i = tid; i < 256; i += 1024) hist[i] = 0;
    __syncthreads();
    for (int i = tid; i < NBOX; i += 1024) {
      uint32_t d = dk[i];
      bool match = (((uint64_t)d >> (sh + 8)) == ((uint64_t)P >> (sh + 8)));
      if (match) atomicAdd(&hist[(d >> sh) & 255u], 1u);
    }
    __syncthreads();
    if (tid == 0) {
      uint32_t cum = 0, v = 0;
      for (; v < 255; v++) {
        if (cum + hist[v] >= need) break;
        cum += hist[v];
      }
      sc[0] = v;
      sc[1] = cum;
    }
    __syncthreads();
    need -= sc[1];
    P |= sc[0] << sh;
    __syncthreads();
  }
  uint32_t Dstar = P;
  if (tid == 0) sc[2] = 0;
  __syncthreads();
  for (int i = tid; i < NBOX; i += 1024) {
    uint32_t d = dk[i];
    if (d <= Dstar) {
      uint32_t pos = atomicAdd(&sc[2], 1u);
      if (pos < CAP) cand[pos] = ((uint64_t)d << 32) | (uint32_t)i;
    }
  }
  __syncthreads();
  uint32_t cnt = sc[2] < CAP ? sc[2] : CAP;
  for (uint32_t i = cnt + tid; i < CAP; i += 1024) cand[i] = ~0ull;
  for (int ksz = 2; ksz <= CAP; ksz <<= 1) {
    for (int jsz = ksz >> 1; jsz > 0; jsz >>= 1) {
      __syncthreads();
      for (int i = tid; i < CAP / 2; i += 1024) {
        int aI = ((i / jsz) * jsz * 2) + (i % jsz);
        int bI = aI + jsz;
        uint64_t xv = cand[aI], yv = cand[bI];
        bool up = ((aI & ksz) == 0);
        if ((xv > yv) == up) { cand[aI] = yv; cand[bI] = xv; }
      }
    }
  }
  __syncthreads();
  for (int r = tid; r < NPRE; r += 1024) {
    uint64_t kk = cand[r];
    uint32_t idx = (uint32_t)kk;
    order[(size_t)b * NPRE + r] = idx;
    float4 bx = *(const float4*)(boxes + ((size_t)b * NBOX + idx) * 4);
    *(float4*)(box6k + ((size_t)b * NPRE + r) * 4) = bx;
  }
  for (int wi = tid; wi < NWORD; wi += 1024) {
    unsigned long long m = 0ull;
    for (int bb = 0; bb < 64; bb++) {
      int r = wi * 64 + bb;
      if (r < NPRE) {
        uint32_t d = (uint32_t)(cand[r] >> 32);
        if (d < 0xFF800000u) m |= (1ull << bb);   // score > -inf
      }
    }
    validm[b * NWORD + wi] = m;
  }
}

// ---------------- NMS suppression bitmask ----------------------------------
__global__ __launch_bounds__(256) void k_mask(const float* __restrict__ box6k,
                                              unsigned long long* __restrict__ mask) {
  int b = blockIdx.z, it = blockIdx.x, wt = blockIdx.y;
  int t = threadIdx.x;
  int il = t & 31, wl = t >> 5;
  __shared__ float bi[32][4];
  __shared__ float bj[512][4];
  if (t < 128) {
    int ii = it * 32 + (t >> 2);
    if (ii > NPRE - 1) ii = NPRE - 1;
    bi[t >> 2][t & 3] = box6k[((size_t)b * NPRE + ii) * 4 + (t & 3)];
  }
#pragma unroll
  for (int q = 0; q < 2; q++) {
    int v = t + 256 * q;
    int jg = wt * 512 + v;
    float4 f = make_float4(0.f, 0.f, 0.f, 0.f);
    if (jg < NPRE) f = *(const float4*)(box6k + ((size_t)b * NPRE + jg) * 4);
    *(float4*)&bj[v][0] = f;
  }
  __syncthreads();
  int i = it * 32 + il;
  int w = wt * 8 + wl;
  if (i >= NPRE || w >= NWORD) return;
  float y1 = bi[il][0], x1 = bi[il][1], y2 = bi[il][2], x2 = bi[il][3];
  float ar = (y2 - y1) * (x2 - x1);
  unsigned long long m = 0ull;
  int jbase = w * 64;
  for (int jj = 0; jj < 64; jj++) {
    int j = jbase + jj;
    int js = wl * 64 + jj;
    float jy1 = bj[js][0], jx1 = bj[js][1], jy2 = bj[js][2], jx2 = bj[js][3];
    float tlY = fmaxf(y1, jy1), tlX = fmaxf(x1, jx1);
    float brY = fminf(y2, jy2), brX = fminf(x2, jx2);
    float ih = fmaxf(brY - tlY, 0.f), iw2 = fmaxf(brX - tlX, 0.f);
    float inter = ih * iw2;
    float arj = (jy2 - jy1) * (jx2 - jx1);
    float iou = inter / (ar + arj - inter);
    if (iou > 0.7f && j > i && j < NPRE) m |= (1ull << jj);
  }
  mask[((size_t)b * NPRE + i) * NWORD + w] = m;
}

// ---------------- sequential NMS scan + output (one wave per batch) --------
__global__ void k_scan(const unsigned long long* __restrict__ mask,
                       const unsigned long long* __restrict__ validm,
                       const float* __restrict__ box6k, float* __restrict__ out) {
  int b = blockIdx.x;
  int lane = threadIdx.x;
  const unsigned long long* mb = mask + (size_t)b * NPRE * NWORD;
  unsigned long long rm0 = 0ull, rm1 = 0ull;
  unsigned long long v0 = (lane < NWORD) ? validm[b * NWORD + lane] : 0ull;
  unsigned long long v1 = (lane + 64 < NWORD) ? validm[b * NWORD + lane + 64] : 0ull;
  __shared__ int keptIdx[NPOST];
  int cnt = 0;
  for (int i = 0; i < NPRE; i++) {
    int w = i >> 6, bp = i & 63;
    unsigned long long rw = (w < 64) ? __shfl(rm0, w) : __shfl(rm1, w - 64);
    unsigned long long vw = (w < 64) ? __shfl(v0, w) : __shfl(v1, w - 64);
    bool keep = ((vw >> bp) & 1ull) && !((rw >> bp) & 1ull);
    if (keep) {
      if (lane == 0) keptIdx[cnt] = i;
      cnt++;
      if (cnt >= NPOST) break;
      unsigned long long m0 = (lane < NWORD) ? mb[(size_t)i * NWORD + lane] : 0ull;
      unsigned long long m1 = (lane + 64 < NWORD) ? mb[(size_t)i * NWORD + lane + 64] : 0ull;
      rm0 |= m0;
      rm1 |= m1;
    }
  }
  __syncthreads();
  for (int r = lane; r < NPOST; r += 64) {
    float4 bx = make_float4(0.f, 0.f, 0.f, 0.f);
    if (r < cnt) bx = *(const float4*)(box6k + ((size_t)b * NPRE + keptIdx[r]) * 4);
    *(float4*)(out + O_ROIS + ((size_t)b * NPOST + r) * 4) = bx;
    out[O_RIDX + b * NPOST + r] = (float)b;
  }
}

extern "C" void kernel_launch(void* const* d_in, const int* in_sizes, int n_in,
                              void* d_out, int out_size, void* d_ws, size_t ws_size,
                              hipStream_t stream) {
  const float* x       = (const float*)d_in[0];
  const float* conv1_w = (const float*)d_in[1];
  const float* conv1_b = (const float*)d_in[2];
  const float* score_w = (const float*)d_in[3];
  const float* score_b = (const float*)d_in[4];
  const float* loc_w   = (const float*)d_in[5];
  const float* loc_b   = (const float*)d_in[6];
  const int* ihp = (const int*)d_in[7];
  const int* iwp = (const int*)d_in[8];
  float* out = (float*)d_out;
  char* ws = (char*)d_ws;
  _Float16* xt1 = (_Float16*)(ws + WO_XT1);
  _Float16* xt2 = (_Float16*)(ws + WO_XT2);
  _Float16* wsA = (_Float16*)(ws + WO_WSA);
  _Float16* wsB = (_Float16*)(ws + WO_WSB);
  float* featP = (float*)(ws + WO_FEATP);
  float* wt    = (float*)(ws + WO_WT);
  float* boxes = (float*)(ws + WO_BOXES);
  uint32_t* dkey  = (uint32_t*)(ws + WO_DKEY);
  float* box6k = (float*)(ws + WO_BOX6K);
  unsigned long long* validm = (unsigned long long*)(ws + WO_VALID);
  unsigned long long* mask   = (unsigned long long*)(ws + WO_MASK);
  uint32_t* order = dkey;   // reuse (order unused downstream; keep ptr distinct-safe)

  k_zero<<<2048, 256, 0, stream>>>((u32*)xt1);
  k_xT<<<dim3(8, 50, NB), 256, 0, stream>>>(x, xt1, xt2);
  k_splitw<<<2048, 256, 0, stream>>>(conv1_w, wsA, wsB);
  k_wt<<<(128 * 56 * 4 + 255) / 256, 256, 0, stream>>>(loc_w, score_w, wt);
  k_conv<<<dim3(22, 4, NB * 2), 256, 0, stream>>>(xt1, xt2, wsA, wsB, featP);
  k_heads<<<(NB * PIX + 3) / 4, 256, 0, stream>>>(featP, wt, conv1_b, loc_b, score_b,
                                                  ihp, iwp, out, boxes, dkey);
  hipFuncSetAttribute((const void*)k_topk, hipFuncAttributeMaxDynamicSharedMemorySize,
                      CAP * 8 + 4096);
  k_topk<<<NB, 1024, CAP * 8 + 4096, stream>>>(dkey, boxes, order, box6k, validm);
  dim3 gm(188, 12, NB);
  k_mask<<<gm, 256, 0, stream>>>(box6k, mask);
  k_scan<<<NB, 64, 0, stream>>>(mask, validm, box6k, out);
}

// Round 3
// 766.526 us; speedup vs baseline: 2.1999x; 1.2320x over previous
//
#include <hip/hip_runtime.h>
#include <stdint.h>

#define NB 4
#define CIN 512
#define PIX 2500
#define KTOT 4608
#define NBOX 22500
#define NPRE 6000
#define NPOST 300
#define NWORD 94
#define CAP 16384

#define O_LOCS   0
#define O_SCORES 360000
#define O_ROIS   540000
#define O_RIDX   544800
#define O_ANCH   546000

// xT geometry: per image, 64 front-slack + 2704 body + 192 back-slack pixel rows, 512 ch fp16
#define XT_ROWS 2960
#define XT_FRONT 64
#define XT_IMG (XT_ROWS * 512)          // fp16 elements per image
#define XT_SPLIT_BYTES ((size_t)NB * XT_IMG * 2)   // 12,124,160

// workspace offsets (bytes)
#define WO_XT1   0ull
#define WO_XT2   12124160ull
#define WO_WSA   24248320ull
#define WO_WSB   28966912ull
#define WO_FEATP 33685504ull            // 2 ksplits x 4 b x 2500 p x 512 oc fp32 = 40,960,000
#define WO_WT    74645504ull
#define WO_BOXES 74760192ull
#define WO_DKEY  76200192ull
#define WO_BOX6K 76560192ull
#define WO_VALID 76944192ull
#define WO_MASK  0ull                   // aliases xT (dead after conv)

#define FEATP_HALF 5120000              // floats per ksplit

typedef _Float16 h8 __attribute__((ext_vector_type(8)));
typedef float f16a __attribute__((ext_vector_type(16)));
typedef unsigned int u32;
typedef unsigned long long u64;

__device__ __forceinline__ void gll16(const void* g, void* l) {
  __builtin_amdgcn_global_load_lds((const __attribute__((address_space(1))) u32*)g,
                                   (__attribute__((address_space(3))) u32*)l, 16, 0, 0);
}

__device__ __forceinline__ float rd_dim(const int* p) {
  int v = *p;
  if (v > 0 && v < 1000000) return (float)v;
  return __int_as_float(v);
}

// ---------------- zero xT (both splits, incl. slack + borders) --------------
__global__ void k_zero(u32* __restrict__ xt) {
  size_t n = (2 * XT_SPLIT_BYTES) / 4;
  for (size_t i = blockIdx.x * 256ull + threadIdx.x; i < n; i += (size_t)gridDim.x * 256)
    xt[i] = 0u;
}

// ---------------- split + transpose x -> xT[b][pix][ic] fp16 hi/lo ---------
__global__ void k_xT(const float* __restrict__ x, _Float16* __restrict__ x1,
                     _Float16* __restrict__ x2) {
  __shared__ float sx[3200];            // [64 ic][50 c]
  int chunk = blockIdx.x, r0 = blockIdx.y, b = blockIdx.z;
  int t = threadIdx.x;
  int ic0 = chunk * 64;
  for (int i = t; i < 3200; i += 256) {
    int icl = i / 50, c = i - icl * 50;
    sx[i] = x[(((size_t)b * 512 + ic0 + icl) * 50 + r0) * 50 + c];
  }
  __syncthreads();
  for (int j = t; j < 3200; j += 256) {
    int c = j >> 6, icl = j & 63;
    float v = sx[icl * 50 + c];
    _Float16 h1 = (_Float16)v;
    _Float16 h2 = (_Float16)(v - (float)h1);
    size_t dst = (size_t)b * XT_IMG + (size_t)(XT_FRONT + (r0 + 1) * 52 + (c + 1)) * 512 + ic0 + icl;
    x1[dst] = h1;
    x2[dst] = h2;
  }
}

// ---------------- split + reorder weights: ws[oc][tap*512+ic] fp16 ---------
__global__ void k_splitw(const float* __restrict__ w, _Float16* __restrict__ wA,
                         _Float16* __restrict__ wB) {
  int n = 512 * KTOT;
  for (int idx = blockIdx.x * 256 + threadIdx.x; idx < n; idx += gridDim.x * 256) {
    int oc = idx / KTOT;
    int rem = idx - oc * KTOT;
    int tp = rem >> 9, ic = rem & 511;
    float v = w[((size_t)oc * 512 + ic) * 9 + tp];
    _Float16 h1 = (_Float16)v;
    wA[idx] = h1;
    wB[idx] = (_Float16)(v - (float)h1);
  }
}

// ---------------- pack head weights: wt[(c4*56+j)*4+i] = W[j][c4*4+i] ------
__global__ void k_wt(const float* __restrict__ loc_w, const float* __restrict__ score_w,
                     float* __restrict__ wt) {
  int idx = blockIdx.x * 256 + threadIdx.x;
  if (idx >= 128 * 56 * 4) return;
  int i = idx & 3, j = (idx >> 2) % 56, c4 = idx / 224;
  int c = c4 * 4 + i;
  float v = 0.f;
  if (j < 36) v = loc_w[(size_t)j * 512 + c];
  else if (j < 54) v = score_w[(size_t)(j - 36) * 512 + c];
  wt[idx] = v;
}

// ---------------- conv via split-fp16 MFMA, K-split 2, partial fp32 --------
// 1-D grid, XCD-pinned: id&7 == bz so each XCD works one (b,ks) working set.
__global__ __launch_bounds__(256, 4) void k_conv(
    const _Float16* __restrict__ xs1, const _Float16* __restrict__ xs2,
    const _Float16* __restrict__ wsA, const _Float16* __restrict__ wsB,
    float* __restrict__ featP) {
  __shared__ _Float16 lds[16384];       // 32 regions x 1KB (64 lanes x 16B)
  int id = blockIdx.x;
  int bz = id & 7;                      // XCD-pinned (b,ks)
  int inner = id >> 3;                  // 0..87
  int mt = inner / 22, nt = inner - mt * 22;
  int b = bz >> 1, ks = bz & 1;
  int t = threadIdx.x, lane = t & 63, w = t >> 6;
  int mh = w & 1, nh = w >> 1;
  int mb = mt * 128, nb = nt * 128;
  int l31 = lane & 31, l5 = lane >> 5;
  const _Float16* xi1 = xs1 + (size_t)b * XT_IMG + (size_t)XT_FRONT * 512;
  const _Float16* xi2 = xs2 + (size_t)b * XT_IMG + (size_t)XT_FRONT * 512;

  f16a acc[2][2];
#pragma unroll
  for (int i = 0; i < 2; i++)
#pragma unroll
    for (int j = 0; j < 2; j++)
#pragma unroll
      for (int e = 0; e < 16; e++) acc[i][j][e] = 0.f;

  for (int kk = 0; kk < 72; kk++) {
    int kb = ks * 2304 + kk * 32;
    int tap = kb >> 9, ic0 = kb & 511;
    int off = (tap / 3 - 1) * 52 + (tap % 3) - 1;
    __syncthreads();                     // prev readers done before overwrite
    // stage 32 x 1KB regions in fragment-linear order (8 issues per wave)
#pragma unroll
    for (int u = 0; u < 8; u++) {
      int i = w * 8 + u;
      if (i < 16) {                      // A region: s=i>>3, ms=(i>>1)&3, k16=i&1
        int s = i >> 3, ms = (i >> 1) & 3, k16 = i & 1;
        const _Float16* wp = s ? wsB : wsA;
        const _Float16* src = wp + (size_t)(mb + ms * 32 + l31) * KTOT + kb + k16 * 16 + l5 * 8;
        gll16(src, &lds[i * 512]);
      } else {                           // B region
        int j = i - 16;
        int s = j >> 3, ns = (j >> 1) & 3, k16 = j & 1;
        const _Float16* xp = s ? xi2 : xi1;
        int qp = nb + ns * 32 + l31 + off;
        const _Float16* src = xp + (ptrdiff_t)qp * 512 + ic0 + k16 * 16 + l5 * 8;
        gll16(src, &lds[(16 + j) * 512]);
      }
    }
    __syncthreads();                     // vmcnt(0) drain -> LDS tiles ready
    h8 af[2][2][2], bf[2][2][2];         // [split][frag][k16]
#pragma unroll
    for (int s = 0; s < 2; s++)
#pragma unroll
      for (int f = 0; f < 2; f++)
#pragma unroll
        for (int k16 = 0; k16 < 2; k16++) {
          int ms = mh * 2 + f, ns = nh * 2 + f;
          af[s][f][k16] = *(const h8*)&lds[((s * 4 + ms) * 2 + k16) * 512 + lane * 8];
          bf[s][f][k16] = *(const h8*)&lds[(16 + (s * 4 + ns) * 2 + k16) * 512 + lane * 8];
        }
#pragma unroll
    for (int k16 = 0; k16 < 2; k16++)
#pragma unroll
      for (int mf = 0; mf < 2; mf++)
#pragma unroll
        for (int nf = 0; nf < 2; nf++) {
          acc[mf][nf] = __builtin_amdgcn_mfma_f32_32x32x16_f16(af[0][mf][k16], bf[0][nf][k16], acc[mf][nf], 0, 0, 0);
          acc[mf][nf] = __builtin_amdgcn_mfma_f32_32x32x16_f16(af[0][mf][k16], bf[1][nf][k16], acc[mf][nf], 0, 0, 0);
          acc[mf][nf] = __builtin_amdgcn_mfma_f32_32x32x16_f16(af[1][mf][k16], bf[0][nf][k16], acc[mf][nf], 0, 0, 0);
        }
  }

  float* fp = featP + (size_t)ks * FEATP_HALF;
#pragma unroll
  for (int mf = 0; mf < 2; mf++)
#pragma unroll
    for (int nf = 0; nf < 2; nf++) {
      int q = nb + nh * 64 + nf * 32 + l31;
      int r = q / 52, c = q - r * 52;
      if (r >= 1 && r <= 50 && c >= 1 && c <= 50) {
        int p = (r - 1) * 50 + (c - 1);
        int oc0 = mb + mh * 64 + mf * 32 + 4 * l5;
        size_t base = ((size_t)b * PIX + p) * 512 + oc0;
#pragma unroll
        for (int g = 0; g < 4; g++) {
          float4 v = make_float4(acc[mf][nf][4 * g + 0], acc[mf][nf][4 * g + 1],
                                 acc[mf][nf][4 * g + 2], acc[mf][nf][4 * g + 3]);
          *(float4*)&fp[base + 8 * g] = v;
        }
      }
    }
}

// ---------------- heads: sum partials + bias + relu, 54 dots, decode -------
__global__ __launch_bounds__(256) void k_heads(const float* __restrict__ featP,
                                               const float* __restrict__ wt4,
                                               const float* __restrict__ conv_b,
                                               const float* __restrict__ loc_b,
                                               const float* __restrict__ score_b,
                                               const int* __restrict__ ihp,
                                               const int* __restrict__ iwp,
                                               float* __restrict__ out,
                                               float* __restrict__ boxes,
                                               uint32_t* __restrict__ dkey) {
  int wid = blockIdx.x * 4 + (threadIdx.x >> 6);
  if (wid >= NB * PIX) return;
  int lane = threadIdx.x & 63;
  int b = wid / PIX, p = wid % PIX;
  int row = lane < 54 ? lane : 54;
  const float* f0 = featP + ((size_t)b * PIX + p) * 512;
  const float* f1 = f0 + FEATP_HALF;
  float acc = 0.f;
  for (int c4 = 0; c4 < 128; c4++) {
    float4 u = *(const float4*)(f0 + c4 * 4);
    float4 v = *(const float4*)(f1 + c4 * 4);
    float4 bb = *(const float4*)(conv_b + c4 * 4);
    float4 wv = *(const float4*)(wt4 + ((size_t)c4 * 56 + row) * 4);
    acc += fmaxf(u.x + v.x + bb.x, 0.f) * wv.x;
    acc += fmaxf(u.y + v.y + bb.y, 0.f) * wv.y;
    acc += fmaxf(u.z + v.z + bb.z, 0.f) * wv.z;
    acc += fmaxf(u.w + v.w + bb.w, 0.f) * wv.w;
  }
  float bi = 0.f;
  if (lane < 36) bi = loc_b[lane];
  else if (lane < 54) bi = score_b[lane - 36];
  acc += bi;
  if (lane < 36) out[O_LOCS + (size_t)b * 90000 + (size_t)p * 36 + lane] = acc;
  else if (lane < 54) out[O_SCORES + (size_t)b * 45000 + (size_t)p * 18 + (lane - 36)] = acc;

  float imgH = rd_dim(ihp), imgW = rd_dim(iwp);
  int gy = p % 50, gx = p / 50;           // transposed-anchor pairing (meshgrid 'ij')
  float sy = 16.f * gy, sx = 16.f * gx;

  int a9 = (lane < 9) ? lane : 0;
  float dy  = __shfl(acc, a9 * 4 + 0);
  float dxv = __shfl(acc, a9 * 4 + 1);
  float dh  = __shfl(acc, a9 * 4 + 2);
  float dw  = __shfl(acc, a9 * 4 + 3);
  float l0  = __shfl(acc, 36 + a9 * 2);
  float l1  = __shfl(acc, 36 + a9 * 2 + 1);

  {
    float rr = (a9 < 3) ? 0.5f : (a9 < 6 ? 1.f : 2.f);
    int si = a9 % 3;
    float ssc = (si == 0) ? 8.f : (si == 1 ? 16.f : 32.f);
    float hb = 16.f * ssc * sqrtf(rr);
    float wb = 16.f * ssc * sqrtf(1.f / rr);
    float ay1 = (8.f - hb * 0.5f) + sy;
    float ax1 = (8.f - wb * 0.5f) + sx;
    float ay2 = (8.f + hb * 0.5f) + sy;
    float ax2 = (8.f + wb * 0.5f) + sx;
    float h = ay2 - ay1, w2d = ax2 - ax1;
    float cy = ay1 + 0.5f * h, cx = ax1 + 0.5f * w2d;
    float cy2 = dy * h + cy, cx2 = dxv * w2d + cx;
    float h2 = expf(dh) * h, ww2 = expf(dw) * w2d;
    float y1 = cy2 - 0.5f * h2, x1 = cx2 - 0.5f * ww2;
    float y2 = cy2 + 0.5f * h2, x2 = cx2 + 0.5f * ww2;
    y1 = fminf(fmaxf(y1, 0.f), imgH);
    x1 = fminf(fmaxf(x1, 0.f), imgW);
    y2 = fminf(fmaxf(y2, 0.f), imgH);
    x2 = fminf(fmaxf(x2, 0.f), imgW);
    bool valid = (y2 - y1 >= 16.f) && (x2 - x1 >= 16.f);
    float m = fmaxf(l0, l1);
    float e0 = expf(l0 - m), e1 = expf(l1 - m);
    float fg = e1 / (e0 + e1);
    float scv = valid ? fg : -INFINITY;
    if (lane < 9) {
      size_t k = (size_t)b * NBOX + (size_t)p * 9 + a9;
      *(float4*)(boxes + k * 4) = make_float4(y1, x1, y2, x2);
      uint32_t u = __float_as_uint(scv);
      uint32_t f2 = (u >> 31) ? ~u : (u | 0x80000000u);
      dkey[k] = ~f2;   // ascending d == descending score
    }
  }
  if (b == 0 && lane < 36) {
    int aa = lane >> 2, dd = lane & 3;
    float rr2 = (aa < 3) ? 0.5f : (aa < 6 ? 1.f : 2.f);
    int si2 = aa % 3;
    float ss2 = (si2 == 0) ? 8.f : (si2 == 1 ? 16.f : 32.f);
    float hb2 = 16.f * ss2 * sqrtf(rr2);
    float wb2 = 16.f * ss2 * sqrtf(1.f / rr2);
    float v;
    if (dd == 0) v = (8.f - hb2 * 0.5f) + sy;
    else if (dd == 1) v = (8.f - wb2 * 0.5f) + sx;
    else if (dd == 2) v = (8.f + hb2 * 0.5f) + sy;
    else v = (8.f + wb2 * 0.5f) + sx;
    out[O_ANCH + (size_t)p * 36 + lane] = v;
  }
}

// ---------------- exact top-6000 (radix-select + bitonic), per batch -------
__global__ void k_topk(const uint32_t* __restrict__ dkey, const float* __restrict__ boxes,
                       float* __restrict__ box6k,
                       unsigned long long* __restrict__ validm) {
  extern __shared__ char smem[];
  uint64_t* cand = (uint64_t*)smem;
  uint32_t* hist = (uint32_t*)(smem + (size_t)CAP * 8);
  uint32_t* sc = hist + 256;
  int b = blockIdx.x, tid = threadIdx.x;
  const uint32_t* dk = dkey + (size_t)b * NBOX;
  uint32_t P = 0, need = NPRE;
  for (int pass = 0; pass < 4; pass++) {
    int sh = 24 - 8 * pass;
    for (int i = tid; i < 256; i += 1024) hist[i] = 0;
    __syncthreads();
    for (int i = tid; i < NBOX; i += 1024) {
      uint32_t d = dk[i];
      bool match = (((uint64_t)d >> (sh + 8)) == ((uint64_t)P >> (sh + 8)));
      if (match) atomicAdd(&hist[(d >> sh) & 255u], 1u);
    }
    __syncthreads();
    if (tid == 0) {
      uint32_t cum = 0, v = 0;
      for (; v < 255; v++) {
        if (cum + hist[v] >= need) break;
        cum += hist[v];
      }
      sc[0] = v;
      sc[1] = cum;
    }
    __syncthreads();
    need -= sc[1];
    P |= sc[0] << sh;
    __syncthreads();
  }
  uint32_t Dstar = P;
  if (tid == 0) sc[2] = 0;
  __syncthreads();
  for (int i = tid; i < NBOX; i += 1024) {
    uint32_t d = dk[i];
    if (d <= Dstar) {
      uint32_t pos = atomicAdd(&sc[2], 1u);
      if (pos < CAP) cand[pos] = ((uint64_t)d << 32) | (uint32_t)i;
    }
  }
  __syncthreads();
  uint32_t cnt = sc[2] < CAP ? sc[2] : CAP;
  // dynamic sort size: cnt >= 6000 always, so S in {8192, 16384}
  int S = 8192;
  while (S < (int)cnt) S <<= 1;
  for (int i = (int)cnt + tid; i < S; i += 1024) cand[i] = ~0ull;
  for (int ksz = 2; ksz <= S; ksz <<= 1) {
    for (int jsz = ksz >> 1; jsz > 0; jsz >>= 1) {
      __syncthreads();
      for (int i = tid; i < S / 2; i += 1024) {
        int aI = ((i / jsz) * jsz * 2) + (i % jsz);
        int bI = aI + jsz;
        uint64_t xv = cand[aI], yv = cand[bI];
        bool up = ((aI & ksz) == 0);
        if ((xv > yv) == up) { cand[aI] = yv; cand[bI] = xv; }
      }
    }
  }
  __syncthreads();
  for (int r = tid; r < NPRE; r += 1024) {
    uint64_t kk = cand[r];
    uint32_t idx = (uint32_t)kk;
    float4 bx = *(const float4*)(boxes + ((size_t)b * NBOX + idx) * 4);
    *(float4*)(box6k + ((size_t)b * NPRE + r) * 4) = bx;
  }
  for (int wi = tid; wi < NWORD; wi += 1024) {
    unsigned long long m = 0ull;
    for (int bb = 0; bb < 64; bb++) {
      int r = wi * 64 + bb;
      if (r < NPRE) {
        uint32_t d = (uint32_t)(cand[r] >> 32);
        if (d < 0xFF800000u) m |= (1ull << bb);   // score > -inf
      }
    }
    validm[b * NWORD + wi] = m;
  }
}

// ---------------- NMS suppression bitmask ----------------------------------
__global__ __launch_bounds__(256) void k_mask(const float* __restrict__ box6k,
                                              unsigned long long* __restrict__ mask) {
  int b = blockIdx.z, it = blockIdx.x, wt = blockIdx.y;
  int t = threadIdx.x;
  int il = t & 31, wl = t >> 5;
  // fast path: whole block below diagonal (all j <= all i) -> mask words are 0
  if (wt * 512 + 511 <= it * 32) {
    int i = it * 32 + il, w = wt * 8 + wl;
    if (i < NPRE && w < NWORD)
      mask[((size_t)b * NPRE + i) * NWORD + w] = 0ull;
    return;
  }
  __shared__ float bi[32][4];
  __shared__ float bj[512][4];
  if (t < 128) {
    int ii = it * 32 + (t >> 2);
    if (ii > NPRE - 1) ii = NPRE - 1;
    bi[t >> 2][t & 3] = box6k[((size_t)b * NPRE + ii) * 4 + (t & 3)];
  }
#pragma unroll
  for (int q = 0; q < 2; q++) {
    int v = t + 256 * q;
    int jg = wt * 512 + v;
    float4 f = make_float4(0.f, 0.f, 0.f, 0.f);
    if (jg < NPRE) f = *(const float4*)(box6k + ((size_t)b * NPRE + jg) * 4);
    *(float4*)&bj[v][0] = f;
  }
  __syncthreads();
  int i = it * 32 + il;
  int w = wt * 8 + wl;
  if (i >= NPRE || w >= NWORD) return;
  float y1 = bi[il][0], x1 = bi[il][1], y2 = bi[il][2], x2 = bi[il][3];
  float ar = (y2 - y1) * (x2 - x1);
  unsigned long long m = 0ull;
  int jbase = w * 64;
  for (int jj = 0; jj < 64; jj++) {
    int j = jbase + jj;
    int js = wl * 64 + jj;
    float jy1 = bj[js][0], jx1 = bj[js][1], jy2 = bj[js][2], jx2 = bj[js][3];
    float tlY = fmaxf(y1, jy1), tlX = fmaxf(x1, jx1);
    float brY = fminf(y2, jy2), brX = fminf(x2, jx2);
    float ih = fmaxf(brY - tlY, 0.f), iw2 = fmaxf(brX - tlX, 0.f);
    float inter = ih * iw2;
    float arj = (jy2 - jy1) * (jx2 - jx1);
    float iou = inter / (ar + arj - inter);
    if (iou > 0.7f && j > i && j < NPRE) m |= (1ull << jj);
  }
  mask[((size_t)b * NPRE + i) * NWORD + w] = m;
}

// ---------------- NMS scan: bit-skip over kept candidates only -------------
__global__ void k_scan(const unsigned long long* __restrict__ mask,
                       const unsigned long long* __restrict__ validm,
                       const float* __restrict__ box6k, float* __restrict__ out) {
  int b = blockIdx.x;
  int lane = threadIdx.x;               // 64 threads = 1 wave
  const unsigned long long* mb = mask + (size_t)b * NPRE * NWORD;
  // avail: lane owns word `lane` (a0) and word `lane+64` (a1); bit set = still eligible
  u64 a0 = (lane < NWORD) ? validm[b * NWORD + lane] : 0ull;
  u64 a1 = (lane + 64 < NWORD) ? validm[b * NWORD + lane + 64] : 0ull;
  __shared__ int keptIdx[NPOST];
  int cnt = 0;
  while (cnt < NPOST) {
    int i;
    u64 bal0 = __ballot(a0 != 0ull);
    if (bal0) {
      int lw = __builtin_ctzll(bal0);
      u64 wv = __shfl(a0, lw);
      i = (lw << 6) + __builtin_ctzll(wv);
    } else {
      u64 bal1 = __ballot(a1 != 0ull);
      if (!bal1) break;
      int lw = __builtin_ctzll(bal1);
      u64 wv = __shfl(a1, lw);
      i = ((lw + 64) << 6) + __builtin_ctzll(wv);
    }
    if (lane == 0) keptIdx[cnt] = i;
    cnt++;
    if (cnt >= NPOST) break;
    // suppress everything box i dominates, and clear bit i itself
    u64 m0 = mb[(size_t)i * NWORD + lane];                       // words 0..63
    u64 m1 = (lane < NWORD - 64) ? mb[(size_t)i * NWORD + 64 + lane] : 0ull;
    a0 &= ~m0;
    a1 &= ~m1;
    int wI = i >> 6, bI = i & 63;
    if (wI < 64) { if (lane == wI) a0 &= ~(1ull << bI); }
    else         { if (lane == wI - 64) a1 &= ~(1ull << bI); }
  }
  __syncthreads();
  for (int r = lane; r < NPOST; r += 64) {
    float4 bx = make_float4(0.f, 0.f, 0.f, 0.f);
    if (r < cnt) bx = *(const float4*)(box6k + ((size_t)b * NPRE + keptIdx[r]) * 4);
    *(float4*)(out + O_ROIS + ((size_t)b * NPOST + r) * 4) = bx;
    out[O_RIDX + b * NPOST + r] = (float)b;
  }
}

extern "C" void kernel_launch(void* const* d_in, const int* in_sizes, int n_in,
                              void* d_out, int out_size, void* d_ws, size_t ws_size,
                              hipStream_t stream) {
  const float* x       = (const float*)d_in[0];
  const float* conv1_w = (const float*)d_in[1];
  const float* conv1_b = (const float*)d_in[2];
  const float* score_w = (const float*)d_in[3];
  const float* score_b = (const float*)d_in[4];
  const float* loc_w   = (const float*)d_in[5];
  const float* loc_b   = (const float*)d_in[6];
  const int* ihp = (const int*)d_in[7];
  const int* iwp = (const int*)d_in[8];
  float* out = (float*)d_out;
  char* ws = (char*)d_ws;
  _Float16* xt1 = (_Float16*)(ws + WO_XT1);
  _Float16* xt2 = (_Float16*)(ws + WO_XT2);
  _Float16* wsA = (_Float16*)(ws + WO_WSA);
  _Float16* wsB = (_Float16*)(ws + WO_WSB);
  float* featP = (float*)(ws + WO_FEATP);
  float* wt    = (float*)(ws + WO_WT);
  float* boxes = (float*)(ws + WO_BOXES);
  uint32_t* dkey  = (uint32_t*)(ws + WO_DKEY);
  float* box6k = (float*)(ws + WO_BOX6K);
  unsigned long long* validm = (unsigned long long*)(ws + WO_VALID);
  unsigned long long* mask   = (unsigned long long*)(ws + WO_MASK);

  k_zero<<<2048, 256, 0, stream>>>((u32*)xt1);
  k_xT<<<dim3(8, 50, NB), 256, 0, stream>>>(x, xt1, xt2);
  k_splitw<<<2048, 256, 0, stream>>>(conv1_w, wsA, wsB);
  k_wt<<<(128 * 56 * 4 + 255) / 256, 256, 0, stream>>>(loc_w, score_w, wt);
  k_conv<<<704, 256, 0, stream>>>(xt1, xt2, wsA, wsB, featP);
  k_heads<<<(NB * PIX + 3) / 4, 256, 0, stream>>>(featP, wt, conv1_b, loc_b, score_b,
                                                  ihp, iwp, out, boxes, dkey);
  hipFuncSetAttribute((const void*)k_topk, hipFuncAttributeMaxDynamicSharedMemorySize,
                      CAP * 8 + 4096);
  k_topk<<<NB, 1024, CAP * 8 + 4096, stream>>>(dkey, boxes, box6k, validm);
  dim3 gm(188, 12, NB);
  k_mask<<<gm, 256, 0, stream>>>(box6k, mask);
  k_scan<<<NB, 64, 0, stream>>>(mask, validm, box6k, out);
}